// Round 4
// baseline (802.527 us; speedup 1.0000x reference)
//
#include <hip/hip_runtime.h>
#include <hip/hip_bf16.h>

typedef unsigned short bf16_t;
typedef __bf16 bf16x8 __attribute__((ext_vector_type(8)));
typedef float f32x4 __attribute__((ext_vector_type(4)));

__device__ __forceinline__ unsigned short f2bf(float x){
  union { __hip_bfloat16 h; unsigned short u; } c;
  c.h = __float2bfloat16(x);
  return c.u;
}
__device__ __forceinline__ float bf2f(bf16_t u){
  union { unsigned short u; __hip_bfloat16 h; } c;
  c.u = u;
  return __bfloat162float(c.h);
}

#define GL2L(g, l) __builtin_amdgcn_global_load_lds( \
    (const __attribute__((address_space(1))) unsigned int*)(g), \
    (__attribute__((address_space(3))) unsigned int*)(l), 16, 0, 0)

// Packed tile format: tile = 128 rows x 32 k of bf16 = 8KB, stored as the
// exact LDS image: byte = r*64 + cs*16 + e*2, cs = c ^ ((r>>1)&3), k = c*8+e.
// Matrix = tiles[rowTile*KT + kTile]. GEMM staging reads are fully contiguous.
__device__ __forceinline__ size_t pidx(int m, int k, int KT){
  const int r = m & 127, c = (k >> 3) & 3;
  const int cs = c ^ ((r >> 1) & 3);
  return ((size_t)((m >> 7)*KT + (k >> 5)))*4096 + r*32 + cs*8 + (k & 7);
}

// ---------------------------------------------------------------------------
// bf16 MFMA GEMM on packed operands. 128x128 tile, BK=32, 4 waves (2x2),
// 4x4 frags of v_mfma_f32_16x16x32_bf16. 4-deep pipelined K-loop: counted
// vmcnt (8/4/0), one raw s_barrier per step, stage(t+3) after the barrier.
// MAP=0: blockIdx=(col,row,ks) id%8=col%8 (XCD colocation, colTiles%8==0)
// MAP=1: blockIdx=(ks,col,row) id%8=ks (split-K XCD streams)
// ACT: 0 = f32 store at bks*csplit offset; 4 = bf16 store with bias.
// ---------------------------------------------------------------------------
template<int ACT, int MAP>
__global__ __launch_bounds__(256)
void gemm_bf16(const bf16_t* __restrict__ Apk, int KTA, int ka0,
               const bf16_t* __restrict__ Bpk, int KTB,
               float* __restrict__ C, int ldc, size_t csplit,
               const float* __restrict__ bias,
               int M, int KchunkT)
{
  __shared__ __align__(16) bf16_t As[4][128*32];
  __shared__ __align__(16) bf16_t Bs[4][128*32];
  const int tid = threadIdx.x;
  const int w = tid >> 6, lane = tid & 63;
  const int wm = w >> 1, wn = w & 1;
  const int lr = lane & 15, kq = lane >> 4;
  int bcol, brow, bks;
  if (MAP == 0) { bcol = blockIdx.x; brow = blockIdx.y; bks = blockIdx.z; }
  else          { bks = blockIdx.x;  bcol = blockIdx.y; brow = blockIdx.z; }
  const int gm0 = brow * 128, gn0 = bcol * 128;
  const int nt = KchunkT;
  const int kbase = bks * KchunkT;

  const bf16_t* Agt = Apk + ((size_t)brow*KTA + ka0 + kbase)*4096 + (w << 10) + (lane << 3);
  const bf16_t* Bgt = Bpk + ((size_t)bcol*KTB + kbase)*4096 + (w << 10) + (lane << 3);

  auto STAGEF = [&](int t) {
    const int bsel = t & 3;
    char* al = (char*)(&As[bsel][0]) + w*2048;
    char* bl = (char*)(&Bs[bsel][0]) + w*2048;
    const bf16_t* ag = Agt + (size_t)t*4096;
    const bf16_t* bg = Bgt + (size_t)t*4096;
    GL2L(ag, al);       GL2L(ag + 512, al + 1024);
    GL2L(bg, bl);       GL2L(bg + 512, bl + 1024);
  };

  STAGEF(0);
  if (nt > 1) STAGEF(1);
  if (nt > 2) STAGEF(2);

  const int kqs = kq ^ ((lr >> 1) & 3);     // swizzled 16B col for frag reads
  f32x4 acc[4][4] = {};

  for (int t = 0; t < nt; ++t) {
    const int rem = nt - t;
    if (rem >= 3)      { asm volatile("s_waitcnt vmcnt(8)" ::: "memory"); }
    else if (rem == 2) { asm volatile("s_waitcnt vmcnt(4)" ::: "memory"); }
    else               { asm volatile("s_waitcnt vmcnt(0)" ::: "memory"); }
    __builtin_amdgcn_s_barrier();           // tile t in LDS, t-1 consumed
    __builtin_amdgcn_sched_barrier(0);
    if (t + 3 < nt) STAGEF(t + 3);          // overwrites tile t-1's buffer
    const int bsel = t & 3;
    const char* Ab = (const char*)(&As[bsel][0]);
    const char* Bb = (const char*)(&Bs[bsel][0]);
    bf16x8 af[4], bfr[4];
#pragma unroll
    for (int mi = 0; mi < 4; mi++)
      af[mi] = *(const bf16x8*)(Ab + ((wm*64 + mi*16 + lr) << 6) + (kqs << 4));
#pragma unroll
    for (int ni = 0; ni < 4; ni++)
      bfr[ni] = *(const bf16x8*)(Bb + ((wn*64 + ni*16 + lr) << 6) + (kqs << 4));
    __builtin_amdgcn_s_setprio(1);
#pragma unroll
    for (int mi = 0; mi < 4; mi++)
#pragma unroll
      for (int ni = 0; ni < 4; ni++)
        acc[mi][ni] = __builtin_amdgcn_mfma_f32_16x16x32_bf16(af[mi], bfr[ni], acc[mi][ni], 0, 0, 0);
    __builtin_amdgcn_s_setprio(0);
    __builtin_amdgcn_sched_barrier(0);
  }

  // epilogue: D row = kq*4 + i, col = lane&15 per 16x16 frag
#pragma unroll
  for (int mi = 0; mi < 4; mi++) {
#pragma unroll
    for (int ni = 0; ni < 4; ni++) {
      const int col = gn0 + wn*64 + ni*16 + lr;
      const float bv = (ACT == 4) ? bias[col] : 0.f;
#pragma unroll
      for (int i = 0; i < 4; i++) {
        const int row = gm0 + wm*64 + mi*16 + kq*4 + i;
        if (row < M) {
          const float v = acc[mi][ni][i] + bv;
          if (ACT == 4) ((bf16_t*)C)[(size_t)row*ldc + col] = f2bf(v);
          else C[(size_t)bks*csplit + (size_t)row*ldc + col] = v;
        }
      }
    }
  }
}

// pack A: src [M][srcldK] f32 row-major -> packed tiles (row, k), clamped rows
__global__ void pack_a(const float* __restrict__ src, bf16_t* __restrict__ dst,
                       int M, int srcldK, int KT)
{
  const int rt = blockIdx.x, kt = blockIdx.y;
  bf16_t* dt = dst + ((size_t)rt*KT + kt)*4096;
  for (int u = threadIdx.x; u < 512; u += 256) {
    const int r = u >> 2, c = u & 3;
    const int cs = c ^ ((r >> 1) & 3);
    const int gm = min(rt*128 + r, M-1);
    const float4* sp = (const float4*)(src + (size_t)gm*srcldK + kt*32 + c*8);
    const float4 v0 = sp[0], v1 = sp[1];
    *(ushort4*)(dt + r*32 + cs*8)     = make_ushort4(f2bf(v0.x), f2bf(v0.y), f2bf(v0.z), f2bf(v0.w));
    *(ushort4*)(dt + r*32 + cs*8 + 4) = make_ushort4(f2bf(v1.x), f2bf(v1.y), f2bf(v1.z), f2bf(v1.w));
  }
}

// pack B (with transpose): src [K][srcldN] f32; B-row n = src col. Writes
// packed tiles for n-tile (n0t+blockIdx.x), k-tile blockIdx.y. Batched via z.
__global__ void pack_b(const float* __restrict__ src, bf16_t* __restrict__ dst,
                       int srcldN, int KT, int n0t, size_t in_batch, size_t out_batch)
{
  const int ntb = blockIdx.x, kt = blockIdx.y, bz = blockIdx.z;
  src += (size_t)bz * in_batch;
  dst += (size_t)bz * out_batch;
  __shared__ float s[32][132];
  for (int i = threadIdx.x; i < 4096; i += 256) {
    const int kl = i >> 7, nl = i & 127;
    s[kl][nl] = src[(size_t)(kt*32 + kl)*srcldN + ntb*128 + nl];
  }
  __syncthreads();
  bf16_t* dt = dst + ((size_t)(n0t + ntb)*KT + kt)*4096;
  for (int u = threadIdx.x; u < 512; u += 256) {
    const int r = u >> 2, c = u & 3;
    const int cs = c ^ ((r >> 1) & 3);
    *(ushort4*)(dt + r*32 + cs*8) =
      make_ushort4(f2bf(s[c*8+0][r]), f2bf(s[c*8+1][r]), f2bf(s[c*8+2][r]), f2bf(s[c*8+3][r]));
    *(ushort4*)(dt + r*32 + cs*8 + 4) =
      make_ushort4(f2bf(s[c*8+4][r]), f2bf(s[c*8+5][r]), f2bf(s[c*8+6][r]), f2bf(s[c*8+7][r]));
  }
}

// sum split-K partials, add bias -> prop f32 + packed X right half
__global__ void reduce_compress(const float* __restrict__ part, const float* __restrict__ bias,
                                float* __restrict__ prop, bf16_t* __restrict__ Xp)
{
  const int idx = blockIdx.x*256 + threadIdx.x;   // < 921600
  const int m = idx >> 10, d = idx & 1023;
  float v = bias[d];
#pragma unroll
  for (int z = 0; z < 8; z++) v += part[(size_t)z*921600 + idx];
  prop[idx] = v;
  Xp[pidx(m, 1024 + d, 64)] = f2bf(v);
}

// RZ split-2 reduce: v = sigmoid(p0+p1+bias). col<1024 (r): Xh right half
// packed = bf16(r*prop); col>=1024 (z): Zbuf compact f32.
__global__ void reduce_rz(const float* __restrict__ part, const float* __restrict__ bias,
                          const float* __restrict__ prop, float* __restrict__ Zbuf,
                          bf16_t* __restrict__ Xhp)
{
  const int idx = blockIdx.x*256 + threadIdx.x;   // < 1843200
  const int m = idx >> 11, c = idx & 2047;
  float v = part[idx] + part[1843200 + idx] + bias[c];
  v = 1.f / (1.f + __expf(-v));
  if (c < 1024) Xhp[pidx(m, 1024 + c, 64)] = f2bf(v * prop[(size_t)m*1024 + c]);
  else          Zbuf[(size_t)m*1024 + (c - 1024)] = v;
}

// h split-4 reduce: h_hat = tanh(sum+bh); prop = (1-z)*prop + z*h_hat;
// write prop f32 + packed X right half.
__global__ void reduce_h(const float* __restrict__ part, const float* __restrict__ bias,
                         const float* __restrict__ Zbuf, float* __restrict__ prop,
                         bf16_t* __restrict__ Xp)
{
  const int idx = blockIdx.x*256 + threadIdx.x;   // < 921600
  const int m = idx >> 10, d = idx & 1023;
  float v = bias[d];
#pragma unroll
  for (int z = 0; z < 4; z++) v += part[(size_t)z*921600 + idx];
  v = tanhf(v);
  const float zz = Zbuf[idx];
  const float pn = (1.f - zz)*prop[idx] + zz*v;
  prop[idx] = pn;
  Xp[pidx(m, 1024 + d, 64)] = f2bf(pn);
}

// u_row[e][h] = sum_d W_edge[e][h][d]*W_att[e][d]; u_col with W_att[e][1024+d]
__global__ void compute_u(const float* __restrict__ We, const float* __restrict__ Wa,
                          float* __restrict__ u_row, float* __restrict__ u_col)
{
  const int w = threadIdx.x >> 6, lane = threadIdx.x & 63;
  const int idx = blockIdx.x*4 + w;               // grid=1792 -> idx<7168
  const int e = idx >> 10, h = idx & 1023;
  const float* wep = We + ((size_t)e*1024 + h)*1024;
  const float* wr  = Wa + (size_t)e*2048;
  const float* wc  = wr + 1024;
  float ar = 0.f, ac = 0.f;
#pragma unroll
  for (int t = 0; t < 16; t++) {
    const float v = wep[lane + 64*t];
    ar += v*wr[lane + 64*t];
    ac += v*wc[lane + 64*t];
  }
  for (int off = 32; off; off >>= 1) { ar += __shfl_down(ar, off); ac += __shfl_down(ac, off); }
  if (lane == 0) { u_row[idx] = ar; u_col[idx] = ac; }
}

// crc[e] = b_edge[e].Wa_row[e], crc[7+e] = b_edge[e].Wa_col[e]
__global__ void crc_kernel(const float* __restrict__ be, const float* __restrict__ Wa,
                           float* __restrict__ crc)
{
  const int w = threadIdx.x >> 6, lane = threadIdx.x & 63;
  for (int idx = w; idx < 14; idx += 4) {
    const int e = idx >> 1, which = idx & 1;
    const float* bp = be + e*1024;
    const float* wp = Wa + (size_t)e*2048 + which*1024;
    float a = 0.f;
#pragma unroll
    for (int t = 0; t < 16; t++) a += bp[lane + 64*t]*wp[lane + 64*t];
    for (int off = 32; off; off >>= 1) a += __shfl_down(a, off);
    if (lane == 0) crc[which*7 + e] = a;
  }
}

// scores[b,e,i,j] = sigmoid(row[i]+col[j]+b_att[e]+crc_row[e]+crc_col[e])
__global__ void attn_kernel(const float* __restrict__ prop, const float* __restrict__ u_row,
                            const float* __restrict__ u_col, const float* __restrict__ crc,
                            const float* __restrict__ b_att, float* __restrict__ scores)
{
  const int b = blockIdx.x, e = blockIdx.y;
  __shared__ float rowv[15], colv[15];
  const int w = threadIdx.x >> 6, lane = threadIdx.x & 63;
  const float* ur = u_row + (size_t)e*1024;
  const float* uc = u_col + (size_t)e*1024;
  for (int n = w; n < 15; n += 4) {
    const float* pr = prop + (size_t)(b*15 + n)*1024;
    float ar = 0.f, ac = 0.f;
#pragma unroll
    for (int t = 0; t < 16; t++) {
      const float pv = pr[lane + 64*t];
      ar += pv*ur[lane + 64*t];
      ac += pv*uc[lane + 64*t];
    }
    for (int off = 32; off; off >>= 1) { ar += __shfl_down(ar, off); ac += __shfl_down(ac, off); }
    if (lane == 0) { rowv[n] = ar; colv[n] = ac; }
  }
  __syncthreads();
  const float base = b_att[e] + crc[e] + crc[7 + e];
  for (int idx = threadIdx.x; idx < 225; idx += 256) {
    const int i = idx/15, j = idx - i*15;
    const float s = 1.f / (1.f + __expf(-(rowv[i] + colv[j] + base)));
    scores[((size_t)(b*7 + e)*15 + i)*15 + j] = s;
  }
}

// merged[b,i,d] = sum_e sum_j scores[b,e,i,j]*msg[b*15+j, e*1024+d]
// -> packed X left half AND packed Xh left half
__global__ void merged_kernel(const bf16_t* __restrict__ msg, const float* __restrict__ scores,
                              bf16_t* __restrict__ Xp, bf16_t* __restrict__ Xhp)
{
  const int b = blockIdx.x, c = blockIdx.y;   // c: 128-wide d-chunk, 8 chunks
  __shared__ float ms[15*7*128];              // [j][e][dl]
  __shared__ float sc[1575];                  // [e][i][j]
  for (int q = threadIdx.x; q < 3360; q += 256) {
    const int idx = q*4;
    const int j = idx / 896;
    const int rem = idx - j*896;
    const int e = rem >> 7, dl = rem & 127;
    const ushort4 v = *(const ushort4*)(msg + (size_t)(b*15 + j)*7168 + e*1024 + c*128 + dl);
    ms[idx]   = bf2f(v.x);
    ms[idx+1] = bf2f(v.y);
    ms[idx+2] = bf2f(v.z);
    ms[idx+3] = bf2f(v.w);
  }
  for (int idx = threadIdx.x; idx < 1575; idx += 256)
    sc[idx] = scores[(size_t)b*1575 + idx];
  __syncthreads();
  for (int oi = threadIdx.x; oi < 1920; oi += 256) {
    const int i = oi >> 7, dl = oi & 127;
    float acc = 0.f;
#pragma unroll
    for (int e = 0; e < 7; e++)
#pragma unroll
      for (int j = 0; j < 15; j++)
        acc += sc[(e*15 + i)*15 + j] * ms[j*896 + e*128 + dl];
    const bf16_t o = f2bf(acc);
    const int m = b*15 + i, k = c*128 + dl;
    Xp [pidx(m, k, 64)] = o;
    Xhp[pidx(m, k, 64)] = o;
  }
}

__global__ void cat2_kernel(const float* __restrict__ a, const float* __restrict__ b,
                            float* __restrict__ o)
{
  const int i = blockIdx.x*256 + threadIdx.x;
  if (i < 1024) o[i] = a[i];
  else if (i < 2048) o[i] = b[i - 1024];
}

// final outputs from last-iteration scores
__global__ void finalize_kernel(const float* __restrict__ scores, float* __restrict__ out)
{
  const int b = blockIdx.x;   // 0..59
  __shared__ float sc[1575];
  __shared__ float act[105];
  __shared__ float asum[15];
  __shared__ float t2[7];
  for (int idx = threadIdx.x; idx < 1575; idx += 256)
    sc[idx] = scores[(size_t)b*1575 + idx];
  __syncthreads();
  for (int idx = threadIdx.x; idx < 105; idx += 256) {
    const int i = idx/7, e = idx - i*7;
    float a = 0.f;
#pragma unroll
    for (int j = 0; j < 15; j++)
      a += (1.f - sc[i*15 + j]) * sc[(e*15 + i)*15 + j];
    act[idx] = a;
    out[(size_t)b*105 + idx] = a;
  }
  for (int idx = threadIdx.x; idx < 225; idx += 256) {
    const int i = idx/15, j = idx - i*15;
    out[6660 + (size_t)b*225 + idx] = 1.f - sc[i*15 + j];
  }
  if (threadIdx.x < 15) {
    const int i = threadIdx.x;
    float s = 0.f;
#pragma unroll
    for (int j = 0; j < 15; j++) s += 1.f - sc[i*15 + j];
    asum[i] = s;
  }
  __syncthreads();
  if (threadIdx.x < 7) {
    const int e = threadIdx.x;
    float t = 0.f;
#pragma unroll
    for (int i = 0; i < 15; i++) t += act[i*7 + e]*asum[i];
    t2[e] = t;
  }
  __syncthreads();
  if (threadIdx.x == 0) {
    float mx = -1e30f;
    for (int e = 1; e < 7; e++) mx = fmaxf(mx, t2[e]);
    float s = 0.f, ex[6];
    for (int e = 1; e < 7; e++) { ex[e-1] = __expf(t2[e] - mx); s += ex[e-1]; }
    for (int e = 1; e < 7; e++) out[6300 + (size_t)b*6 + (e-1)] = ex[e-1]/s;
  }
}

extern "C" void kernel_launch(void* const* d_in, const int* in_sizes, int n_in,
                              void* d_out, int out_size, void* d_ws, size_t ws_size,
                              hipStream_t stream)
{
  const float* pose = (const float*)d_in[0];
  const float* Wc   = (const float*)d_in[1];
  const float* bc   = (const float*)d_in[2];
  const float* We   = (const float*)d_in[3];
  const float* be   = (const float*)d_in[4];
  const float* Wa   = (const float*)d_in[5];
  const float* ba   = (const float*)d_in[6];
  const float* Wr   = (const float*)d_in[7];
  const float* br   = (const float*)d_in[8];
  const float* Wz   = (const float*)d_in[9];
  const float* bz   = (const float*)d_in[10];
  const float* Wh   = (const float*)d_in[11];
  const float* bh   = (const float*)d_in[12];
  float* out = (float*)d_out;

  // ---- workspace carving ----
  char* p = (char*)d_ws;
  auto alloc = [&](size_t b) { char* r = p; p += (b + 255) & ~(size_t)255; return r; };
  // packed persistent operands
  bf16_t* Wedgep = (bf16_t*)alloc(56ull*32*8192);    // 14.7 MB  [56 nt][32 kt]
  bf16_t* Wrzp   = (bf16_t*)alloc(16ull*64*8192);    //  8.4 MB  [16 nt][64 kt]
  bf16_t* Whp    = (bf16_t*)alloc(8ull*64*8192);     //  4.2 MB  [8 nt][64 kt]
  bf16_t* Xp     = (bf16_t*)alloc(8ull*64*8192);     //  4.2 MB  [merged|prop]
  bf16_t* Xhp    = (bf16_t*)alloc(8ull*64*8192);     //  4.2 MB  [merged|r*prop]
  float*  prop   = (float*) alloc(900ull*1024*4);    //  3.7 MB f32 master state
  float*  scores = (float*) alloc(60ull*7*15*15*4);
  float*  u_row  = (float*) alloc(7168*4);
  float*  u_col  = (float*) alloc(7168*4);
  float*  crc    = (float*) alloc(64);
  float*  brzv   = (float*) alloc(2048*4);
  // phase-union region:
  // phase1 (compress): Apk 52.4 + Wcp 52.4 + partial 29.5 = 134.3 MB
  // phase2 (iters):    msgb 12.9 | Zbuf 3.7 | partRZ 14.8 | partH 14.8 = 46 MB
  char* r1 = alloc(134400000ull);
  bf16_t* Apk     = (bf16_t*)r1;                             // [8 rt][800 kt]
  bf16_t* Wcp     = (bf16_t*)(r1 + 52428800ull);             // [8 nt][800 kt]
  float*  partial = (float*) (r1 + 2ull*52428800ull);        // 8 x 900x1024 f32
  bf16_t* msgb    = (bf16_t*)r1;                             // 900x7168 bf16
  float*  Zbuf    = (float*) (r1 + 12902400ull);
  float*  partRZ  = (float*) (r1 + 12902400ull + 3686400ull);
  float*  partH   = (float*) (r1 + 12902400ull + 3686400ull + 14745600ull);

  // ---- precompute: pack all GEMM operands into tile format ----
  compute_u<<<1792, 256, 0, stream>>>(We, Wa, u_row, u_col);
  crc_kernel<<<1, 256, 0, stream>>>(be, Wa, crc);
  cat2_kernel<<<8, 256, 0, stream>>>(br, bz, brzv);
  pack_a<<<dim3(8,800), 256, 0, stream>>>(pose, Apk, 900, 25600, 800);
  pack_b<<<dim3(8,800), 256, 0, stream>>>(Wc, Wcp, 1024, 800, 0, 0, 0);
  pack_b<<<dim3(8,32,7), 256, 0, stream>>>(We, Wedgep, 1024, 32, 0,
                                           1024ull*1024, 8ull*32*4096);
  pack_b<<<dim3(8,64), 256, 0, stream>>>(Wr, Wrzp, 1024, 64, 0, 0, 0);
  pack_b<<<dim3(8,64), 256, 0, stream>>>(Wz, Wrzp, 1024, 64, 8, 0, 0);
  pack_b<<<dim3(8,64), 256, 0, stream>>>(Wh, Whp, 1024, 64, 0, 0, 0);

  // compress: prop = pose @ W_compress + b_compress  (split-K=8, id%8=ksplit)
  gemm_bf16<0,1><<<dim3(8,8,8), 256, 0, stream>>>(Apk, 800, 0, Wcp, 800,
      partial, 1024, 921600ull, nullptr, 900, 100);
  reduce_compress<<<3600, 256, 0, stream>>>(partial, bc, prop, Xp);

  // ---- 6 recurrent iterations (last one: scores only) ----
  for (int it = 0; it < 6; it++) {
    attn_kernel<<<dim3(60,7), 256, 0, stream>>>(prop, u_row, u_col, crc, ba, scores);
    if (it == 5) break;
    // msg = prop @ W_edge + b_edge  (A = X right half: ka0=32)
    gemm_bf16<4,0><<<dim3(56,8,1), 256, 0, stream>>>(Xp, 64, 32, Wedgep, 32,
        (float*)msgb, 7168, 0, be, 900, 32);
    merged_kernel<<<dim3(60,8), 256, 0, stream>>>(msgb, scores, Xp, Xhp);
    // [r|z] partials = X @ [Wr|Wz]   (split-K=2 -> 256 blocks)
    gemm_bf16<0,0><<<dim3(16,8,2), 256, 0, stream>>>(Xp, 64, 0, Wrzp, 64,
        partRZ, 2048, 1843200ull, nullptr, 900, 32);
    reduce_rz<<<7200, 256, 0, stream>>>(partRZ, brzv, prop, Zbuf, Xhp);
    // h partials = Xh @ Wh  (split-K=4 -> 256 blocks)
    gemm_bf16<0,0><<<dim3(8,8,4), 256, 0, stream>>>(Xhp, 64, 0, Whp, 64,
        partH, 1024, 921600ull, nullptr, 900, 16);
    reduce_h<<<3600, 256, 0, stream>>>(partH, bh, Zbuf, prop, Xp);
  }

  finalize_kernel<<<60, 256, 0, stream>>>(scores, out);
}